// Round 6
// baseline (238.426 us; speedup 1.0000x reference)
//
#include <hip/hip_runtime.h>
#include <math.h>

typedef __attribute__((ext_vector_type(8))) short short8;
typedef __attribute__((ext_vector_type(4))) float f32x4;

#define NTOK 32768          // B*L
#define DDIM 1024
#define HDIM 64
#define NB 16
#define LN_EPS 1e-5f

#define IDX_OFF ((size_t)NTOK * NB)            // 524288
#define AUX_OFF (IDX_OFF + (size_t)NTOK * 2)   // 589824
#define WT_OFF  (AUX_OFF + 1)                  // 589825

// ws (float) layout:
//   [0:16) cnt accum   [16:32) Psum accum   (gacc, zeroed by memset)
//   [4352 : +98304) B-pack: 3 terms x 32 ksteps x 4 ntiles x 64 lanes x 4 dw
#define BP_F   4352

__device__ __forceinline__ short8 as_s8(uint4 u) {
    union { uint4 u; short8 s; } x; x.u = u; return x.s;
}

// async global->LDS, 16B per lane (LDS dest wave-uniform base + lane*16).
__device__ __forceinline__ void gld16(const void* g, float* l) {
    __builtin_amdgcn_global_load_lds(
        (const __attribute__((address_space(1))) void*)g,
        (__attribute__((address_space(3))) void*)l, 16, 0, 0);
}

// B-pack only (3-term bf16 split of gamma*W1, MFMA B-frag order).
// Colsums moved into router_main phase 0 (no ws atomics needed).
__global__ void pack_kernel(const float* __restrict__ W1,
                            const float* __restrict__ gamma,
                            float* __restrict__ ws) {
    const int s = blockIdx.x;           // k-range 32s..32s+31
    const int t = threadIdx.x;          // 256
    unsigned int* bp = (unsigned int*)(ws + BP_F);
    const int n = t >> 6;               // n-tile
    const int l = t & 63;               // frag lane
    const int q = l >> 4, c = l & 15;
    const int col = n * 16 + c;
    unsigned int uh[8], um[8], ul[8];
#pragma unroll
    for (int j = 0; j < 8; ++j) {
        const int k = s * 32 + q * 8 + j;
        const float w = gamma[k] * W1[k * HDIM + col];
        const unsigned int hb = __float_as_uint(w) & 0xFFFF0000u;
        const float r = w - __uint_as_float(hb);
        const unsigned int mb = __float_as_uint(r) & 0xFFFF0000u;
        const float r2 = r - __uint_as_float(mb);
        const unsigned int lb = __float_as_uint(r2) & 0xFFFF0000u;
        uh[j] = hb >> 16; um[j] = mb >> 16; ul[j] = lb >> 16;
    }
    const int base = ((s * 4 + n) * 64 + l) * 4;
#pragma unroll
    for (int d = 0; d < 4; ++d) {
        bp[base + d]         = uh[2 * d] | (uh[2 * d + 1] << 16);
        bp[32768 + base + d] = um[2 * d] | (um[2 * d + 1] << 16);
        bp[65536 + base + d] = ul[2 * d] | (ul[2 * d + 1] << 16);
    }
}

// 3-term truncated-bf16 split of 8 floats + LN-stat accumulation.
__device__ __forceinline__ void split8(const f32x4 a0, const f32x4 a1,
                                       short8& AH, short8& AM, short8& AL,
                                       float& s1, float& s2) {
    const float v[8] = {a0.x, a0.y, a0.z, a0.w, a1.x, a1.y, a1.z, a1.w};
    unsigned int ph[4], pm[4], pl[4];
#pragma unroll
    for (int d = 0; d < 4; ++d) {
        const float v0 = v[2 * d], v1 = v[2 * d + 1];
        const unsigned int h0 = __float_as_uint(v0) & 0xFFFF0000u;
        const unsigned int h1 = __float_as_uint(v1) & 0xFFFF0000u;
        const float r0 = v0 - __uint_as_float(h0);
        const float r1 = v1 - __uint_as_float(h1);
        const unsigned int m0 = __float_as_uint(r0) & 0xFFFF0000u;
        const unsigned int m1 = __float_as_uint(r1) & 0xFFFF0000u;
        const float q0 = r0 - __uint_as_float(m0);
        const float q1 = r1 - __uint_as_float(m1);
        ph[d] = (h0 >> 16) | h1;
        pm[d] = (m0 >> 16) | m1;
        pl[d] = (__float_as_uint(q0) >> 16) | (__float_as_uint(q1) & 0xFFFF0000u);
        s1 += v0 + v1;
        s2 = fmaf(v0, v0, fmaf(v1, v1, s2));
    }
    AH = as_s8(make_uint4(ph[0], ph[1], ph[2], ph[3]));
    AM = as_s8(make_uint4(pm[0], pm[1], pm[2], pm[3]));
    AL = as_s8(make_uint4(pl[0], pl[1], pl[2], pl[3]));
}

#define MFMA6(ACC, AH, AM, AL, BH, BM, BL)                                        \
    ACC = __builtin_amdgcn_mfma_f32_16x16x32_bf16(AH, as_s8(BH), ACC, 0, 0, 0);   \
    ACC = __builtin_amdgcn_mfma_f32_16x16x32_bf16(AH, as_s8(BM), ACC, 0, 0, 0);   \
    ACC = __builtin_amdgcn_mfma_f32_16x16x32_bf16(AM, as_s8(BH), ACC, 0, 0, 0);   \
    ACC = __builtin_amdgcn_mfma_f32_16x16x32_bf16(AH, as_s8(BL), ACC, 0, 0, 0);   \
    ACC = __builtin_amdgcn_mfma_f32_16x16x32_bf16(AM, as_s8(BM), ACC, 0, 0, 0);   \
    ACC = __builtin_amdgcn_mfma_f32_16x16x32_bf16(AL, as_s8(BH), ACC, 0, 0, 0);

// publish barrier (rule-#18 fenced)
#define PUB()                                                       \
    asm volatile("s_waitcnt vmcnt(0) lgkmcnt(0)" ::: "memory");     \
    __builtin_amdgcn_s_barrier();                                   \
    __builtin_amdgcn_sched_barrier(0)

// Block = 64 tokens, 4 waves; wave wv owns tokens [wv*16,+16), full K=1024
// as 16 chunks x 2 k-steps. Grid = 512 -> TWO independent blocks/CU (the
// second block covers the other's per-chunk barrier drains). x is loaded
// with PLAIN cached coalesced loads: every prior variant (r0-r5) used
// __builtin_nontemporal_load for x and every one was capped at the same
// ~850 GB/s fetch rate independent of occupancy/pipelining — the nt
// (no-allocate streaming) path is the last invariant shared by all of them.
// A: regs -> single per-wave LDS tile [16 tok][65] (stride 65 = 2-way free
// for BOTH the staging write and the fragment read; r5's stride 68 was an
// 8-way read conflict). Overwrite is guarded by lgkmcnt(0) after COMPUTE.
// B: gld16 double-buffer as before (6 chunks/wave).
// LDS: Bdbuf 12288 fl | A 4x1040 fl | csg/csb 128 | cnt 16 = ~65 KB -> 2/CU.
__global__ __launch_bounds__(256, 2)
void router_main(const float* __restrict__ x,
                 const float* __restrict__ W1,
                 const float* __restrict__ gamma,
                 const float* __restrict__ beta,
                 const unsigned int* __restrict__ bp,   // packed B frags
                 const float* __restrict__ W2,
                 float* __restrict__ gacc,
                 float* __restrict__ out) {
    __shared__ __align__(16) float smem[16592];
    float* csgl = smem + 16448;    // 64
    float* csbl = smem + 16512;    // 64
    float* cntl = smem + 16576;    // 16
    // epilogue aliases (after main loop; staging dead):
    float* w2l  = smem;            // [64][16] = 1024      (aliases Bbuf0)
    float* llds = smem + 1024;     // [64 tok][20] = 1280  (aliases Bbuf0)
    float* hlds = smem + 12288;    // [4 waves][16][65] = 4160 (aliases A)

    const int t    = threadIdx.x;
    const int wv   = t >> 6;                 // 0..3
    const int lane = t & 63;
    const int q = lane >> 4, c = lane & 15;
    const int tok0 = blockIdx.x * 64;
    const int tokw = tok0 + wv * 16;

    // ---- phase 0: per-block colsums csg=colsum(gamma*W1), csb=colsum(beta*W1)
    {
        const int j = t & 63, p = t >> 6;    // 4 k-groups x 64 cols
        float ag = 0.f, ab = 0.f;
#pragma unroll 4
        for (int k = p; k < DDIM; k += 4) {
            const float w = W1[k * HDIM + j];
            ag = fmaf(gamma[k], w, ag);
            ab = fmaf(beta[k],  w, ab);
        }
        float* red = smem + 12288;           // A region, free pre-loop
        red[p * 64 + j] = ag;
        red[256 + p * 64 + j] = ab;
        __syncthreads();
        if (t < 64)
            csgl[t] = red[t] + red[64 + t] + red[128 + t] + red[192 + t];
        else if (t < 128) {
            const int j2 = t - 64;
            csbl[j2] = red[256 + j2] + red[320 + j2] + red[384 + j2] + red[448 + j2];
        }
        if (t < 16) cntl[t] = 0.f;
        __syncthreads();
    }

    // ---- main loop setup
    const int bidx0 = wv * 6;                // B share: 24 units / 4 waves
    // coalesced A source: lane (q,c) covers token (tokw+q+4j), floats c*4..
    const float* xA = x + (size_t)(tokw + q) * DDIM + c * 4;
    float* awb       = smem + 12288 + wv * 1040 + q * 65 + c * 4;   // write
    const float* arb = smem + 12288 + wv * 1040 + c * 65 + q * 8;   // read

#define STAGE_B(CI)                                                              \
    {                                                                            \
        float* dst = smem + ((CI) & 1) * 6144;                                   \
        _Pragma("unroll")                                                        \
        for (int i = 0; i < 6; ++i) {                                            \
            const int idx = bidx0 + i;                                           \
            const int st = (idx >= 12) ? 1 : 0;                                  \
            const int rem = idx - st * 12;                                       \
            const int term = rem >> 2, n = rem & 3;                              \
            gld16(bp + term * 32768 + (2 * (CI) + st) * 1024 + n * 256 + lane*4, \
                  dst + st * 3072 + term * 1024 + n * 256);                      \
        }                                                                        \
    }
#define STAGE_A(CI)                                                              \
    {                                                                            \
        const float* srcA = xA + (CI) * 64;                                      \
        ar0 = *(const f32x4*)(srcA);                                             \
        ar1 = *(const f32x4*)(srcA + 4096);                                      \
        ar2 = *(const f32x4*)(srcA + 8192);                                      \
        ar3 = *(const f32x4*)(srcA + 12288);                                     \
    }
#define DS_WRITE_A()                                                             \
    {                                                                            \
        *(f32x4*)(awb)       = ar0;                                              \
        *(f32x4*)(awb + 260) = ar1;                                              \
        *(f32x4*)(awb + 520) = ar2;                                              \
        *(f32x4*)(awb + 780) = ar3;                                              \
    }
#define COMPUTE(CI)                                                              \
    {                                                                            \
        const float* Bb = smem + ((CI) & 1) * 6144;                              \
        _Pragma("unroll")                                                        \
        for (int st = 0; st < 2; ++st) {                                         \
            const f32x4 a00 = *(const f32x4*)(arb + st * 32);                    \
            const f32x4 a01 = *(const f32x4*)(arb + st * 32 + 4);                \
            short8 AH0, AM0, AL0;                                                \
            split8(a00, a01, AH0, AM0, AL0, s1a, s2a);                           \
            const float* Bs = Bb + st * 3072;                                    \
            _Pragma("unroll")                                                    \
            for (int n = 0; n < 4; ++n) {                                        \
                const uint4 bh = *(const uint4*)(Bs + n * 256 + lane * 4);       \
                const uint4 bm = *(const uint4*)(Bs + 1024 + n * 256 + lane*4);  \
                const uint4 bl = *(const uint4*)(Bs + 2048 + n * 256 + lane*4);  \
                MFMA6(acc[n], AH0, AM0, AL0, bh, bm, bl);                        \
            }                                                                    \
        }                                                                        \
    }

    f32x4 acc[4] = {{0.f,0.f,0.f,0.f},{0.f,0.f,0.f,0.f},{0.f,0.f,0.f,0.f},{0.f,0.f,0.f,0.f}};
    float s1a = 0.f, s2a = 0.f;
    f32x4 ar0, ar1, ar2, ar3;

    // prologue: chunk 0
    STAGE_A(0)
    STAGE_B(0)
    DS_WRITE_A()
    PUB();

#pragma unroll 1
    for (int ci = 0; ci < 16; ++ci) {
        if (ci < 15) {
            STAGE_A(ci + 1)
            STAGE_B(ci + 1)
            __builtin_amdgcn_sched_barrier(0);   // pin staging before compute
        }
        COMPUTE(ci)
        // A-buffer reads must retire before the overwrite below (rule #18)
        asm volatile("s_waitcnt lgkmcnt(0)" ::: "memory");
        __builtin_amdgcn_sched_barrier(0);
        if (ci < 15) {
            DS_WRITE_A()
            PUB();
        }
    }
    __syncthreads();   // staging buffers dead -> epilogue aliases valid

    // LN-stat q-reduction: lane (q,c) holds k-partials for token tokw+c;
    // xor 16/32 combines the 4 q replicas -> full-K stats at lane c.
    s1a += __shfl_xor(s1a, 16, 64); s1a += __shfl_xor(s1a, 32, 64);
    s2a += __shfl_xor(s2a, 16, 64); s2a += __shfl_xor(s2a, 32, 64);

    *(float4*)(w2l + t * 4) = *(const float4*)(W2 + t * 4);

    // stats redistribution + LN fold + exact GELU -> h to LDS.
    {
        float* hw = hlds + wv * 1040;
#pragma unroll
        for (int r = 0; r < 4; ++r) {
            const int tt = q * 4 + r;
            const float S1A = __shfl(s1a, tt, 64), S2A = __shfl(s2a, tt, 64);
            const float muA = S1A * (1.0f / 1024.0f);
            const float rsA = 1.0f / sqrtf(S2A * (1.0f / 1024.0f) - muA * muA + LN_EPS);
#pragma unroll
            for (int n = 0; n < 4; ++n) {
                const float preA = rsA * (acc[n][r] - muA * csgl[n * 16 + c])
                                 + csbl[n * 16 + c];
                hw[tt * 65 + n * 16 + c] =
                    0.5f * preA * (1.0f + erff(preA * 0.70710678118654752f));
            }
        }
    }
    __syncthreads();

    // logits: thread -> (token m2 = t>>2, 4 nb cols)
    {
        const int m2 = t >> 2, o = (t & 3) * 4;
        const float* hrow = hlds + (m2 >> 4) * 1040 + (m2 & 15) * 65;
        f32x4 L0 = {0.f, 0.f, 0.f, 0.f};
#pragma unroll 8
        for (int j = 0; j < 64; ++j) {
            L0 += *(const f32x4*)(w2l + j * 16 + o) * hrow[j];
        }
        *(f32x4*)(llds + m2 * 20 + o) = L0 * 0.5f;   // /TEMP
    }
    __syncthreads();

    // softmax + top-2 + outputs (one thread per token; 64 tokens/block)
    if (t < 64) {
        float p[16];
        float mx = -1e30f;
#pragma unroll
        for (int i = 0; i < NB; ++i) { p[i] = llds[t * 20 + i]; mx = fmaxf(mx, p[i]); }
        float ssum = 0.f;
#pragma unroll
        for (int i = 0; i < NB; ++i) { p[i] = expf(p[i] - mx); ssum += p[i]; }
        const float inv = 1.0f / ssum;
#pragma unroll
        for (int i = 0; i < NB; ++i) { p[i] *= inv; llds[t * 20 + i] = p[i]; }

        float* po = out + (size_t)(tok0 + t) * NB;
#pragma unroll
        for (int u = 0; u < 4; ++u) {
            float4 v; v.x = p[u*4]; v.y = p[u*4+1]; v.z = p[u*4+2]; v.w = p[u*4+3];
            *(float4*)(po + u * 4) = v;
        }

        float b0 = -1.f, b1 = -1.f;
        int i0 = 0, i1 = 0;
#pragma unroll
        for (int i = 0; i < NB; ++i) {
            if (p[i] > b0)      { b1 = b0; i1 = i0; b0 = p[i]; i0 = i; }
            else if (p[i] > b1) { b1 = p[i]; i1 = i; }
        }
        const float wsum = b0 + b1 + 1e-8f;
        out[IDX_OFF + (size_t)(tok0 + t) * 2]     = (float)i0;
        out[IDX_OFF + (size_t)(tok0 + t) * 2 + 1] = (float)i1;
        out[WT_OFF + (size_t)(tok0 + t) * 2]      = b0 / wsum;
        out[WT_OFF + (size_t)(tok0 + t) * 2 + 1]  = b1 / wsum;
        atomicAdd(&cntl[i0], 1.0f);
        atomicAdd(&cntl[i1], 1.0f);
    }
    __syncthreads();

    // aux partials straight into gacc (device-scope atomics; aux_kernel
    // reads after the dispatch boundary)
    if (t < 16) {
        float ps = 0.f;
        for (int m = 0; m < 64; ++m) ps += llds[m * 20 + t];
        atomicAdd(&gacc[t], cntl[t]);
        atomicAdd(&gacc[16 + t], ps);
    }
}

__global__ void aux_kernel(float* __restrict__ gacc,
                           float* __restrict__ out) {
    __shared__ float red[32];
    const int t = threadIdx.x;          // 64
    if (t < 32) red[t] = atomicAdd(&gacc[t], 0.0f);   // coherent read
    __syncthreads();
    if (t == 0) {
        float a = 0.f;
        for (int k = 0; k < NB; ++k) {
            const float f = red[k] / (65536.0f + 1e-8f);
            const float P = red[16 + k] * (1.0f / 32768.0f);
            a += f * P;
        }
        out[AUX_OFF] = 16.0f * a;
    }
}

extern "C" void kernel_launch(void* const* d_in, const int* in_sizes, int n_in,
                              void* d_out, int out_size, void* d_ws, size_t ws_size,
                              hipStream_t stream) {
    const float* x     = (const float*)d_in[0];
    const float* gamma = (const float*)d_in[1];
    const float* beta  = (const float*)d_in[2];
    const float* W1    = (const float*)d_in[3];
    const float* W2    = (const float*)d_in[4];
    float* out = (float*)d_out;
    float* ws  = (float*)d_ws;

    (void)hipMemsetAsync(ws, 0, 192 * sizeof(float), stream);  // gacc
    pack_kernel<<<32, 256, 0, stream>>>(W1, gamma, ws);
    router_main<<<NTOK / 64, 256, 0, stream>>>(x, W1, gamma, beta,
                                               (const unsigned int*)(ws + BP_F),
                                               W2, ws, out);
    aux_kernel<<<1, 64, 0, stream>>>(ws, out);
}

// Round 9
// 221.083 us; speedup vs baseline: 1.0784x; 1.0784x over previous
//
#include <hip/hip_runtime.h>
#include <math.h>

typedef __attribute__((ext_vector_type(8))) short short8;
typedef __attribute__((ext_vector_type(4))) float f32x4;

#define NTOK 32768          // B*L
#define DDIM 1024
#define HDIM 64
#define NB 16
#define LN_EPS 1e-5f

#define IDX_OFF ((size_t)NTOK * NB)            // 524288
#define AUX_OFF (IDX_OFF + (size_t)NTOK * 2)   // 589824
#define WT_OFF  (AUX_OFF + 1)                  // 589825

// ws (float) layout:
//   [0:16) cnt accum  [16:32) Psum accum  (gacc; memset)
//   [64:128) csg = colsum(gamma*W1)  [128:192) csb = colsum(beta*W1)
//   [4352 : +98304) B-pack: 3 terms x 32 ksteps x 4 ntiles x 64 lanes x 4 dw
#define CS_F   64
#define BP_F   4352

__device__ __forceinline__ short8 as_s8(uint4 u) {
    union { uint4 u; short8 s; } x; x.u = u; return x.s;
}

__device__ __forceinline__ f32x4 ntload4(const float* p) {
    return __builtin_nontemporal_load((const f32x4*)p);
}

// Fused: B-pack (3-term bf16 split of gamma*W1, MFMA B-frag order) + colsums
// of gamma*W1 / beta*W1 via atomicAdd (ws[CS_F..] pre-zeroed).
__global__ void pack_kernel(const float* __restrict__ W1,
                            const float* __restrict__ gamma,
                            const float* __restrict__ beta,
                            float* __restrict__ ws) {
    __shared__ float sg[4][64];
    __shared__ float sb[4][64];
    const int s = blockIdx.x;           // k-range 32s..32s+31
    const int t = threadIdx.x;          // 256

    {   // cs partials
        const int j = t & 63, p = t >> 6;
        float ag = 0.f, ab = 0.f;
        for (int kk = 0; kk < 8; ++kk) {
            const int k = s * 32 + p * 8 + kk;
            const float w = W1[k * HDIM + j];
            ag += gamma[k] * w;
            ab += beta[k] * w;
        }
        sg[p][j] = ag;
        sb[p][j] = ab;
    }

    {   // B pack
        unsigned int* bp = (unsigned int*)(ws + BP_F);
        const int n = t >> 6;           // n-tile
        const int l = t & 63;           // frag lane
        const int q = l >> 4, c = l & 15;
        const int col = n * 16 + c;
        unsigned int uh[8], um[8], ul[8];
#pragma unroll
        for (int j = 0; j < 8; ++j) {
            const int k = s * 32 + q * 8 + j;
            const float w = gamma[k] * W1[k * HDIM + col];
            const unsigned int hb = __float_as_uint(w) & 0xFFFF0000u;
            const float r = w - __uint_as_float(hb);
            const unsigned int mb = __float_as_uint(r) & 0xFFFF0000u;
            const float r2 = r - __uint_as_float(mb);
            const unsigned int lb = __float_as_uint(r2) & 0xFFFF0000u;
            uh[j] = hb >> 16; um[j] = mb >> 16; ul[j] = lb >> 16;
        }
        const int base = ((s * 4 + n) * 64 + l) * 4;
#pragma unroll
        for (int d = 0; d < 4; ++d) {
            bp[base + d]         = uh[2 * d] | (uh[2 * d + 1] << 16);
            bp[32768 + base + d] = um[2 * d] | (um[2 * d + 1] << 16);
            bp[65536 + base + d] = ul[2 * d] | (ul[2 * d + 1] << 16);
        }
    }
    __syncthreads();
    if (t < 64) {
        atomicAdd(&ws[CS_F + t],      sg[0][t] + sg[1][t] + sg[2][t] + sg[3][t]);
        atomicAdd(&ws[CS_F + 64 + t], sb[0][t] + sb[1][t] + sb[2][t] + sb[3][t]);
    }
}

// 3-term truncated-bf16 split of 8 floats + LN-stat accumulation.
__device__ __forceinline__ void split8(const f32x4 a0, const f32x4 a1,
                                       short8& AH, short8& AM, short8& AL,
                                       float& s1, float& s2) {
    const float v[8] = {a0.x, a0.y, a0.z, a0.w, a1.x, a1.y, a1.z, a1.w};
    unsigned int ph[4], pm[4], pl[4];
#pragma unroll
    for (int d = 0; d < 4; ++d) {
        const float v0 = v[2 * d], v1 = v[2 * d + 1];
        const unsigned int h0 = __float_as_uint(v0) & 0xFFFF0000u;
        const unsigned int h1 = __float_as_uint(v1) & 0xFFFF0000u;
        const float r0 = v0 - __uint_as_float(h0);
        const float r1 = v1 - __uint_as_float(h1);
        const unsigned int m0 = __float_as_uint(r0) & 0xFFFF0000u;
        const unsigned int m1 = __float_as_uint(r1) & 0xFFFF0000u;
        const float q0 = r0 - __uint_as_float(m0);
        const float q1 = r1 - __uint_as_float(m1);
        ph[d] = (h0 >> 16) | h1;
        pm[d] = (m0 >> 16) | m1;
        pl[d] = (__float_as_uint(q0) >> 16) | (__float_as_uint(q1) & 0xFFFF0000u);
        s1 += v0 + v1;
        s2 = fmaf(v0, v0, fmaf(v1, v1, s2));
    }
    AH = as_s8(make_uint4(ph[0], ph[1], ph[2], ph[3]));
    AM = as_s8(make_uint4(pm[0], pm[1], pm[2], pm[3]));
    AL = as_s8(make_uint4(pl[0], pl[1], pl[2], pl[3]));
}

#define MFMA6(ACC, AH, AM, AL, BH, BM, BL)                                        \
    ACC = __builtin_amdgcn_mfma_f32_16x16x32_bf16(AH, as_s8(BH), ACC, 0, 0, 0);   \
    ACC = __builtin_amdgcn_mfma_f32_16x16x32_bf16(AH, as_s8(BM), ACC, 0, 0, 0);   \
    ACC = __builtin_amdgcn_mfma_f32_16x16x32_bf16(AM, as_s8(BH), ACC, 0, 0, 0);   \
    ACC = __builtin_amdgcn_mfma_f32_16x16x32_bf16(AH, as_s8(BL), ACC, 0, 0, 0);   \
    ACC = __builtin_amdgcn_mfma_f32_16x16x32_bf16(AM, as_s8(BM), ACC, 0, 0, 0);   \
    ACC = __builtin_amdgcn_mfma_f32_16x16x32_bf16(AL, as_s8(BH), ACC, 0, 0, 0);

// Block = 64 tokens, 4 waves, 256 thr; wave wv owns ALL 64 tokens for
// k-quarter [wv*256, +256) = 8 k-steps. Grid = 512 -> 2 blocks/CU = 8
// waves/CU (r0's occupancy). MAIN LOOP IS BARRIER-FREE with B in registers:
// the r0/r1 reg-B kernels ran at the ~6.3 TB/s aggregate VMEM-return
// ceiling (521 MB / 83.8 us); the LDS-B variants moved fewer bytes but
// their per-chunk publish barriers dropped them to 2.9-4.2 TB/s for zero
// net gain. Here tokens/wave doubles 32->64 (acc 4 groups x 4 n = 64 VGPR),
// halving B traffic to 196 MB; total ~330 MB at the demonstrated ceiling
// => ~55 us expected. No inline-asm waitcnt anywhere (r7's race class) —
// compiler-managed waits only; k-quarter combine via LDS (r1-proven).
__global__ __launch_bounds__(256, 2)
void router_main(const float* __restrict__ x,
                 const float* __restrict__ ws_ro,       // csg/csb
                 const unsigned int* __restrict__ bp,   // packed B frags
                 const float* __restrict__ W2,
                 float* __restrict__ gacc,
                 float* __restrict__ out) {
    // floats: ylds[4][64][68]=17408 | csgl 64 | csbl 64 | s1l 256 | s2l 256
    //         | cntl 16  (llds [64][20] aliases ylds[1] after combine;
    //         h [64][68] goes in-place into ylds[0])
    __shared__ __align__(16) float smem[18064];
    float* csgl = smem + 17408;
    float* csbl = smem + 17472;
    float* s1l  = smem + 17536;
    float* s2l  = smem + 17792;
    float* cntl = smem + 18048;
    float* llds = smem + 4352;     // alias ylds[1]

    const int t    = threadIdx.x;
    const int wv   = t >> 6;                 // k-quarter
    const int lane = t & 63;
    const int q = lane >> 4, c = lane & 15;
    const int tok0 = blockIdx.x * 64;

    if (t < 64) csgl[t] = ws_ro[CS_F + t];
    else if (t < 128) csbl[t - 64] = ws_ro[CS_F + 64 + (t - 64)];
    if (t < 16) cntl[t] = 0.f;

    // A sources: group g -> token tok0 + g*16 + c, k base wv*256 + q*8
    const float* xg[4];
#pragma unroll
    for (int g = 0; g < 4; ++g)
        xg[g] = x + (size_t)(tok0 + g * 16 + c) * DDIM + wv * 256 + q * 8;
    const unsigned int* bpl = bp + lane * 4;

    f32x4 acc[4][4];
#pragma unroll
    for (int g = 0; g < 4; ++g)
#pragma unroll
        for (int n = 0; n < 4; ++n) acc[g][n] = (f32x4){0.f, 0.f, 0.f, 0.f};
    float s1g[4] = {0.f, 0.f, 0.f, 0.f};
    float s2g[4] = {0.f, 0.f, 0.f, 0.f};

#pragma unroll 1
    for (int it = 0; it < 8; ++it) {
        const int s = wv * 8 + it;
        // issue all A (8 loads, oldest) then all B (12, youngest): split8
        // waits only on A while B stays in flight under the VALU work.
        f32x4 a0v[4], a1v[4];
#pragma unroll
        for (int g = 0; g < 4; ++g) {
            a0v[g] = ntload4(xg[g] + it * 32);
            a1v[g] = ntload4(xg[g] + it * 32 + 4);
        }
        uint4 bh[4], bm[4], bl[4];
#pragma unroll
        for (int n = 0; n < 4; ++n) {
            bh[n] = *(const uint4*)(bpl + (s * 4 + n) * 256);
            bm[n] = *(const uint4*)(bpl + 32768 + (s * 4 + n) * 256);
            bl[n] = *(const uint4*)(bpl + 65536 + (s * 4 + n) * 256);
        }
#pragma unroll
        for (int g = 0; g < 4; ++g) {
            short8 AH, AM, AL;
            split8(a0v[g], a1v[g], AH, AM, AL, s1g[g], s2g[g]);
#pragma unroll
            for (int n = 0; n < 4; ++n) {
                MFMA6(acc[g][n], AH, AM, AL, bh[n], bm[n], bl[n]);
            }
        }
    }

    // q-reduce LN-stat partials (per group, this wave's k-quarter)
#pragma unroll
    for (int g = 0; g < 4; ++g) {
        s1g[g] += __shfl_xor(s1g[g], 16, 64); s1g[g] += __shfl_xor(s1g[g], 32, 64);
        s2g[g] += __shfl_xor(s2g[g], 16, 64); s2g[g] += __shfl_xor(s2g[g], 32, 64);
    }
    if (lane < 16) {
#pragma unroll
        for (int g = 0; g < 4; ++g) {
            s1l[wv * 64 + g * 16 + c] = s1g[g];
            s2l[wv * 64 + g * 16 + c] = s2g[g];
        }
    }

    // partial y -> ylds[wv]  (C/D: row = g*16 + q*4 + r, col = n*16 + c)
    {
        float* yw = smem + wv * 4352;
#pragma unroll
        for (int g = 0; g < 4; ++g)
#pragma unroll
            for (int n = 0; n < 4; ++n)
#pragma unroll
                for (int r = 0; r < 4; ++r)
                    yw[(g * 16 + q * 4 + r) * 68 + n * 16 + c] = acc[g][n][r];
    }
    __syncthreads();

    // 4-way k-quarter combine + LN fold + exact GELU.
    // thread t: token m = t>>2, 16 cols at cb = (t&3)*16 (16B-aligned, st 68)
    {
        const int m = t >> 2, cb = (t & 3) * 16;
        const float S1 = s1l[m] + s1l[64 + m] + s1l[128 + m] + s1l[192 + m];
        const float S2 = s2l[m] + s2l[64 + m] + s2l[128 + m] + s2l[192 + m];
        const float mu   = S1 * (1.0f / 1024.0f);
        const float var  = S2 * (1.0f / 1024.0f) - mu * mu;
        const float rstd = 1.0f / sqrtf(var + LN_EPS);
        f32x4 yv[4];
#pragma unroll
        for (int k = 0; k < 4; ++k) {
            const int off = m * 68 + cb + k * 4;
            yv[k] = *(const f32x4*)(smem + off)
                  + *(const f32x4*)(smem + 4352 + off)
                  + *(const f32x4*)(smem + 8704 + off)
                  + *(const f32x4*)(smem + 13056 + off);
        }
#pragma unroll
        for (int k = 0; k < 4; ++k)
#pragma unroll
            for (int e = 0; e < 4; ++e) {
                const int col = cb + k * 4 + e;
                const float pre = rstd * (yv[k][e] - mu * csgl[col]) + csbl[col];
                yv[k][e] = 0.5f * pre * (1.0f + erff(pre * 0.70710678118654752f));
            }
        // h in-place into ylds[0] (each (m,col) owned by exactly this thread)
#pragma unroll
        for (int k = 0; k < 4; ++k)
            *(f32x4*)(smem + m * 68 + cb + k * 4) = yv[k];
    }
    __syncthreads();

    // logits: thread -> (token m2 = t>>2, 4 nb cols). W2 straight from L2
    // (4 KB, line-shared across lanes). llds aliases ylds[1] (dead now).
    {
        const int m2 = t >> 2, o = (t & 3) * 4;
        const float* hrow = smem + m2 * 68;
        f32x4 L0 = {0.f, 0.f, 0.f, 0.f};
#pragma unroll 8
        for (int j = 0; j < 64; ++j) {
            L0 += *(const f32x4*)(W2 + j * 16 + o) * hrow[j];
        }
        *(f32x4*)(llds + m2 * 20 + o) = L0 * 0.5f;   // /TEMP
    }
    __syncthreads();

    // softmax + top-2 + outputs (one thread per token; 64 tokens/block)
    if (t < 64) {
        float p[16];
        float mx = -1e30f;
#pragma unroll
        for (int i = 0; i < NB; ++i) { p[i] = llds[t * 20 + i]; mx = fmaxf(mx, p[i]); }
        float ssum = 0.f;
#pragma unroll
        for (int i = 0; i < NB; ++i) { p[i] = expf(p[i] - mx); ssum += p[i]; }
        const float inv = 1.0f / ssum;
#pragma unroll
        for (int i = 0; i < NB; ++i) { p[i] *= inv; llds[t * 20 + i] = p[i]; }

        float* po = out + (size_t)(tok0 + t) * NB;
#pragma unroll
        for (int u = 0; u < 4; ++u) {
            float4 v; v.x = p[u*4]; v.y = p[u*4+1]; v.z = p[u*4+2]; v.w = p[u*4+3];
            *(float4*)(po + u * 4) = v;
        }

        float b0 = -1.f, b1 = -1.f;
        int i0 = 0, i1 = 0;
#pragma unroll
        for (int i = 0; i < NB; ++i) {
            if (p[i] > b0)      { b1 = b0; i1 = i0; b0 = p[i]; i0 = i; }
            else if (p[i] > b1) { b1 = p[i]; i1 = i; }
        }
        const float wsum = b0 + b1 + 1e-8f;
        out[IDX_OFF + (size_t)(tok0 + t) * 2]     = (float)i0;
        out[IDX_OFF + (size_t)(tok0 + t) * 2 + 1] = (float)i1;
        out[WT_OFF + (size_t)(tok0 + t) * 2]      = b0 / wsum;
        out[WT_OFF + (size_t)(tok0 + t) * 2 + 1]  = b1 / wsum;
        atomicAdd(&cntl[i0], 1.0f);
        atomicAdd(&cntl[i1], 1.0f);
    }
    __syncthreads();

    // aux partials straight into gacc (device-scope atomics; aux_kernel
    // reads after the dispatch boundary)
    if (t < 16) {
        float ps = 0.f;
        for (int m = 0; m < 64; ++m) ps += llds[m * 20 + t];
        atomicAdd(&gacc[t], cntl[t]);
        atomicAdd(&gacc[16 + t], ps);
    }
}

__global__ void aux_kernel(float* __restrict__ gacc,
                           float* __restrict__ out) {
    __shared__ float red[32];
    const int t = threadIdx.x;          // 64
    if (t < 32) red[t] = atomicAdd(&gacc[t], 0.0f);   // coherent read
    __syncthreads();
    if (t == 0) {
        float a = 0.f;
        for (int k = 0; k < NB; ++k) {
            const float f = red[k] / (65536.0f + 1e-8f);
            const float P = red[16 + k] * (1.0f / 32768.0f);
            a += f * P;
        }
        out[AUX_OFF] = 16.0f * a;
    }
}

extern "C" void kernel_launch(void* const* d_in, const int* in_sizes, int n_in,
                              void* d_out, int out_size, void* d_ws, size_t ws_size,
                              hipStream_t stream) {
    const float* x     = (const float*)d_in[0];
    const float* gamma = (const float*)d_in[1];
    const float* beta  = (const float*)d_in[2];
    const float* W1    = (const float*)d_in[3];
    const float* W2    = (const float*)d_in[4];
    float* out = (float*)d_out;
    float* ws  = (float*)d_ws;

    (void)hipMemsetAsync(ws, 0, 192 * sizeof(float), stream);  // gacc + cs
    pack_kernel<<<32, 256, 0, stream>>>(W1, gamma, beta, ws);
    router_main<<<NTOK / 64, 256, 0, stream>>>(x, ws, (const unsigned int*)(ws + BP_F),
                                               W2, ws, out);
    aux_kernel<<<1, 64, 0, stream>>>(ws, out);
}